// Round 6
// baseline (215.984 us; speedup 1.0000x reference)
//
#include <hip/hip_runtime.h>

#define TT  200
#define IN  5
#define NH  32
#define FC1 20
#define HS  24   // padded h20 row stride (floats): [0:10)=half0, [12:22)=half1, rest 0

typedef float f2 __attribute__((ext_vector_type(2)));

__device__ __forceinline__ float sigm(float a) {
    return __builtin_amdgcn_rcpf(1.f + __expf(-a));
}
__device__ __forceinline__ float tanh_f(float a) {
    return fmaf(2.f, __builtin_amdgcn_rcpf(1.f + __expf(-2.f * a)), -1.f);
}

// One wave per batch element. Lane l = (u = l&31, p = l>>5).
// K-split across half-waves: lane (u,p) computes the p-half partial dot of
// ALL FOUR gate rows {u,u+32,u+64,u+96}; halves combine with shfl_xor(32).
// After combine each lane holds i,f,g,o of h-row u -> local c/h update.
// h lives in LDS (p0 writes h[u]); h20 precomputed for all T in LDS.
__global__ __launch_bounds__(64, 2) void lstm_fused(
    const float* __restrict__ x,      // [B,200,5]
    const float* __restrict__ fc1_w,  // [20,5]
    const float* __restrict__ fc1_b,  // [20]
    const float* __restrict__ w_ih,   // [128,20]
    const float* __restrict__ w_hh,   // [128,32]
    const float* __restrict__ b_ih,   // [128]
    const float* __restrict__ b_hh,   // [128]
    const float* __restrict__ fc2_w,  // [2,32]
    const float* __restrict__ fc2_b,  // [2]
    float* __restrict__ out)          // [B,2]
{
    const int b = blockIdx.x;
    const int l = threadIdx.x;
    const int u = l & 31;
    const int p = l >> 5;

    __shared__ __align__(16) float h20t[TT * HS];   // 19.2 KB
    __shared__ __align__(16) float sh_h[NH];

    // ---- phase 1: h20 table, zero-padded layout [t][24] ----
    {
        float fw[FC1][IN], fb[FC1];
        #pragma unroll
        for (int j = 0; j < FC1; ++j) {
            #pragma unroll
            for (int i = 0; i < IN; ++i) fw[j][i] = fc1_w[j * IN + i];
            fb[j] = fc1_b[j];
        }
        const float* xb = x + (size_t)b * (TT * IN);
        for (int t = l; t < TT; t += 64) {
            float xv[IN];
            #pragma unroll
            for (int i = 0; i < IN; ++i) xv[i] = xb[t * IN + i];
            float hv[FC1];
            #pragma unroll
            for (int j = 0; j < FC1; ++j) {
                float a = fb[j];
                #pragma unroll
                for (int i = 0; i < IN; ++i) a = fmaf(fw[j][i], xv[i], a);
                hv[j] = fmaxf(a, 0.f);
            }
            float4* dst = (float4*)(h20t + t * HS);
            dst[0] = make_float4(hv[0],  hv[1],  hv[2],  hv[3]);
            dst[1] = make_float4(hv[4],  hv[5],  hv[6],  hv[7]);
            dst[2] = make_float4(hv[8],  hv[9],  0.f,    0.f);
            dst[3] = make_float4(hv[10], hv[11], hv[12], hv[13]);
            dst[4] = make_float4(hv[14], hv[15], hv[16], hv[17]);
            dst[5] = make_float4(hv[18], hv[19], 0.f,    0.f);
        }
    }
    // init h = 0
    if (l < 8) ((float4*)sh_h)[l] = make_float4(0.f, 0.f, 0.f, 0.f);
    __syncthreads();

    // ---- phase 2: weights for 4 rows x this lane's 28 padded dims ----
    // xin slot map: [0:5) = h20 f2 pairs (10 floats), [5] = zero pad pair,
    //               [6:14) = h f2 pairs (16 floats)
    f2 wv[4][14];
    float bias[4];
    #pragma unroll
    for (int j = 0; j < 4; ++j) {
        const int r = u + 32 * j;               // i,f,g,o rows
        const float* wi = w_ih + r * FC1 + 10 * p;
        #pragma unroll
        for (int k = 0; k < 5; ++k) wv[j][k] = f2{wi[2*k], wi[2*k+1]};
        wv[j][5] = f2{0.f, 0.f};
        const float4* wh = (const float4*)(w_hh + r * NH + 16 * p);
        #pragma unroll
        for (int k = 0; k < 4; ++k) {
            float4 v = wh[k];
            wv[j][6 + 2*k]     = f2{v.x, v.y};
            wv[j][6 + 2*k + 1] = f2{v.z, v.w};
        }
        bias[j] = b_ih[r] + b_hh[r];
    }

    // ---- phase 3: recurrence ----
    float c = 0.f;
    for (int t = 0; t < TT; ++t) {
        // this half's inputs: 3 + 4 uniform ds_read_b128
        const float4* hx = (const float4*)(h20t + t * HS + p * 12);
        float4 a0 = hx[0], a1 = hx[1], a2 = hx[2];
        const float4* hh = (const float4*)(sh_h + p * 16);
        float4 b0 = hh[0], b1 = hh[1], b2 = hh[2], b3 = hh[3];

        f2 xin[14];
        xin[0]  = f2{a0.x, a0.y};  xin[1]  = f2{a0.z, a0.w};
        xin[2]  = f2{a1.x, a1.y};  xin[3]  = f2{a1.z, a1.w};
        xin[4]  = f2{a2.x, a2.y};  xin[5]  = f2{a2.z, a2.w};
        xin[6]  = f2{b0.x, b0.y};  xin[7]  = f2{b0.z, b0.w};
        xin[8]  = f2{b1.x, b1.y};  xin[9]  = f2{b1.z, b1.w};
        xin[10] = f2{b2.x, b2.y};  xin[11] = f2{b2.z, b2.w};
        xin[12] = f2{b3.x, b3.y};  xin[13] = f2{b3.z, b3.w};

        float d[4];
        #pragma unroll
        for (int j = 0; j < 4; ++j) {
            f2 s0 = f2{0.f, 0.f}, s1 = f2{0.f, 0.f};
            #pragma unroll
            for (int k = 0; k < 14; k += 2) {
                s0 = __builtin_elementwise_fma(wv[j][k],   xin[k],   s0);
                s1 = __builtin_elementwise_fma(wv[j][k+1], xin[k+1], s1);
            }
            f2 s = s0 + s1;
            d[j] = s.x + s.y;
        }
        // combine the two half-dots; both halves end up with the full sums
        #pragma unroll
        for (int j = 0; j < 4; ++j) d[j] += __shfl_xor(d[j], 32);

        const float gi = sigm(d[0] + bias[0]);
        const float gf = sigm(d[1] + bias[1]);
        const float gg = tanh_f(d[2] + bias[2]);
        const float go = sigm(d[3] + bias[3]);
        c = fmaf(gf, c, gi * gg);
        const float hval = go * tanh_f(c);

        if (p == 0) sh_h[u] = hval;
        __syncthreads();
    }

    // ---- fc2 on final h ----
    if (l < 2) {
        float acc = fc2_b[l];
        #pragma unroll
        for (int k = 0; k < NH; ++k) acc = fmaf(fc2_w[l * NH + k], sh_h[k], acc);
        out[(size_t)b * 2 + l] = acc;
    }
}

extern "C" void kernel_launch(void* const* d_in, const int* in_sizes, int n_in,
                              void* d_out, int out_size, void* d_ws, size_t ws_size,
                              hipStream_t stream) {
    const float* x     = (const float*)d_in[0];
    const float* fc1_w = (const float*)d_in[1];
    const float* fc1_b = (const float*)d_in[2];
    const float* w_ih  = (const float*)d_in[3];
    const float* w_hh  = (const float*)d_in[4];
    const float* b_ih  = (const float*)d_in[5];
    const float* b_hh  = (const float*)d_in[6];
    const float* fc2_w = (const float*)d_in[7];
    const float* fc2_b = (const float*)d_in[8];
    float* out = (float*)d_out;

    const int B = in_sizes[0] / (TT * IN);
    lstm_fused<<<dim3(B), dim3(64), 0, stream>>>(
        x, fc1_w, fc1_b, w_ih, w_hh, b_ih, b_hh, fc2_w, fc2_b, out);
}

// Round 8
// 153.706 us; speedup vs baseline: 1.4052x; 1.4052x over previous
//
#include <hip/hip_runtime.h>

#define TT  200
#define IN  5
#define NH  32
#define FC1 20
#define CH  64        // h20 chunk length (= wave size)
#define RS  12        // h20 chunk row stride in h2 units (48 B, 16B-aligned)

typedef _Float16 h2t __attribute__((ext_vector_type(2)));   // 4 B
typedef _Float16 h4t __attribute__((ext_vector_type(4)));   // 8 B
typedef _Float16 h8t __attribute__((ext_vector_type(8)));   // 16 B

#if __has_builtin(__builtin_amdgcn_fdot2)
#define FDOT2(a, b, c) __builtin_amdgcn_fdot2((a), (b), (c), false)
#else
__device__ __forceinline__ float FDOT2(h2t a, h2t b, float c) {
    return fmaf((float)a.x, (float)b.x, fmaf((float)a.y, (float)b.y, c));
}
#endif

__device__ __forceinline__ float sigm(float a) {
    return __builtin_amdgcn_rcpf(1.f + __expf(-a));
}
__device__ __forceinline__ float tanh_f(float a) {
    return fmaf(2.f, __builtin_amdgcn_rcpf(1.f + __expf(-2.f * a)), -1.f);
}

#define EXT2(dst, src, i0, i1) dst = __builtin_shufflevector(src, src, i0, i1)

// One wave per batch element. Lane l = (u = l&31, p = l>>5).
// Lane owns rows rA = u+32p (i|f) and rB = rA+64 (g|o), full K=52, as 52 f16
// pairs consumed by v_dot2_f32_f16 (f32 accumulate). h + h20 live in LDS as
// f16. h20 chunk-precomputed (64 steps) from SGPR-resident fc1 weights.
__global__ __attribute__((amdgpu_waves_per_eu(4, 4))) __launch_bounds__(64)
void lstm_fused(
    const float* __restrict__ x,      // [B,200,5]
    const float* __restrict__ fc1_w,  // [20,5]
    const float* __restrict__ fc1_b,  // [20]
    const float* __restrict__ w_ih,   // [128,20]
    const float* __restrict__ w_hh,   // [128,32]
    const float* __restrict__ b_ih,   // [128]
    const float* __restrict__ b_hh,   // [128]
    const float* __restrict__ fc2_w,  // [2,32]
    const float* __restrict__ fc2_b,  // [2]
    float* __restrict__ out)          // [B,2]
{
    const int b = blockIdx.x;
    const int l = threadIdx.x;
    const int u = l & 31;
    const int p = l >> 5;

    __shared__ __align__(16) h2t h20c[CH * RS];   // 3 KB, rows of 10 h2 (+2 pad)
    __shared__ __align__(16) _Float16 sh_h[NH];   // 64 B

    // ---- load this lane's two weight rows as f16 pairs (52 VGPRs) ----
    const int rA = u + 32 * p;      // i (p=0) | f (p=1)
    const int rB = rA + 64;         // g (p=0) | o (p=1)
    h2t wA[26], wB[26];             // [w_ih: 10 pairs][w_hh: 16 pairs]
    {
        const float4* pa = (const float4*)(w_ih + rA * FC1);
        const float4* pb = (const float4*)(w_ih + rB * FC1);
        #pragma unroll
        for (int j = 0; j < 5; ++j) {
            float4 va = pa[j], vb = pb[j];
            wA[2*j]   = h2t{(_Float16)va.x, (_Float16)va.y};
            wA[2*j+1] = h2t{(_Float16)va.z, (_Float16)va.w};
            wB[2*j]   = h2t{(_Float16)vb.x, (_Float16)vb.y};
            wB[2*j+1] = h2t{(_Float16)vb.z, (_Float16)vb.w};
        }
        const float4* ca = (const float4*)(w_hh + rA * NH);
        const float4* cb = (const float4*)(w_hh + rB * NH);
        #pragma unroll
        for (int j = 0; j < 8; ++j) {
            float4 va = ca[j], vb = cb[j];
            wA[10+2*j]   = h2t{(_Float16)va.x, (_Float16)va.y};
            wA[10+2*j+1] = h2t{(_Float16)va.z, (_Float16)va.w};
            wB[10+2*j]   = h2t{(_Float16)vb.x, (_Float16)vb.y};
            wB[10+2*j+1] = h2t{(_Float16)vb.z, (_Float16)vb.w};
        }
    }
    const float biasA = b_ih[rA] + b_hh[rA];
    const float biasB = b_ih[rB] + b_hh[rB];

    // second activation: tanh (p=0, g) vs sigmoid (p=1, o)
    const float An = (p == 0) ? 2.f : 1.f;
    const float Bn = (p == 0) ? -2.f : -1.f;
    const float Cn = (p == 0) ? -1.f : 0.f;

    // init h = 0
    if (l < 16) ((unsigned int*)sh_h)[l] = 0u;
    float c = 0.f;

    const float* xb = x + (size_t)b * (TT * IN);

    for (int tc = 0; tc < TT; tc += CH) {
        // ---- refill: lane l computes h20 for t = tc + l ----
        {
            const int t = tc + l;
            if (t < TT) {
                float xv[IN];
                #pragma unroll
                for (int i = 0; i < IN; ++i) xv[i] = xb[t * IN + i];
                h2t* row = h20c + (size_t)l * RS;
                #pragma unroll
                for (int j = 0; j < FC1; j += 2) {
                    // fc1 weights/bias are wave-uniform -> SGPR loads
                    float a0 = fc1_b[j], a1 = fc1_b[j + 1];
                    #pragma unroll
                    for (int i = 0; i < IN; ++i) {
                        a0 = fmaf(fc1_w[j * IN + i],       xv[i], a0);
                        a1 = fmaf(fc1_w[(j + 1) * IN + i], xv[i], a1);
                    }
                    row[j >> 1] = h2t{(_Float16)fmaxf(a0, 0.f),
                                      (_Float16)fmaxf(a1, 0.f)};
                }
            }
        }
        __syncthreads();

        const int te = (TT - tc < CH) ? (TT - tc) : CH;
        for (int k = 0; k < te; ++k) {
            // gather xin = [h20(10 pairs) | h(16 pairs)] via uniform DS reads
            h2t xin[26];
            {
                const h2t* row = h20c + (size_t)k * RS;
                h8t r0 = *(const h8t*)(row);       // pairs 0-3
                h8t r1 = *(const h8t*)(row + 4);   // pairs 4-7
                h4t r2 = *(const h4t*)(row + 8);   // pairs 8-9
                EXT2(xin[0], r0, 0, 1);  EXT2(xin[1], r0, 2, 3);
                EXT2(xin[2], r0, 4, 5);  EXT2(xin[3], r0, 6, 7);
                EXT2(xin[4], r1, 0, 1);  EXT2(xin[5], r1, 2, 3);
                EXT2(xin[6], r1, 4, 5);  EXT2(xin[7], r1, 6, 7);
                EXT2(xin[8], r2, 0, 1);  EXT2(xin[9], r2, 2, 3);
                const h8t* hp = (const h8t*)sh_h;
                h8t h0 = hp[0], h1 = hp[1], h2 = hp[2], h3 = hp[3];
                EXT2(xin[10], h0, 0, 1); EXT2(xin[11], h0, 2, 3);
                EXT2(xin[12], h0, 4, 5); EXT2(xin[13], h0, 6, 7);
                EXT2(xin[14], h1, 0, 1); EXT2(xin[15], h1, 2, 3);
                EXT2(xin[16], h1, 4, 5); EXT2(xin[17], h1, 6, 7);
                EXT2(xin[18], h2, 0, 1); EXT2(xin[19], h2, 2, 3);
                EXT2(xin[20], h2, 4, 5); EXT2(xin[21], h2, 6, 7);
                EXT2(xin[22], h3, 0, 1); EXT2(xin[23], h3, 2, 3);
                EXT2(xin[24], h3, 4, 5); EXT2(xin[25], h3, 6, 7);
            }

            // 52 dot2, 2 chains per row
            float aA0 = biasA, aA1 = 0.f, aB0 = biasB, aB1 = 0.f;
            #pragma unroll
            for (int j = 0; j < 26; j += 2) {
                aA0 = FDOT2(wA[j],     xin[j],     aA0);
                aA1 = FDOT2(wA[j + 1], xin[j + 1], aA1);
                aB0 = FDOT2(wB[j],     xin[j],     aB0);
                aB1 = FDOT2(wB[j + 1], xin[j + 1], aB1);
            }
            const float aA = aA0 + aA1;
            const float aB = aB0 + aB1;

            // s0 = sigmoid(aA) [i|f]; s1 = tanh/sigmoid(aB) [g|o]
            const float s0 = sigm(aA);
            const float e1 = __expf(Bn * aB);
            const float s1 = fmaf(An, __builtin_amdgcn_rcpf(1.f + e1), Cn);

            // exchange with the other half (proven): x0 = other's s0, etc.
            const float x0 = __shfl_xor(s0, 32);
            const float x1 = __shfl_xor(s1, 32);

            // mirrored update: all lanes compute identical c / hval for dim u
            const float ig = (p == 0) ? (s0 * s1) : (x0 * x1);  // i*g
            const float fv = (p == 0) ? x0 : s0;                // f
            const float ov = (p == 0) ? x1 : s1;                // o
            c = fmaf(fv, c, ig);
            const float hval = ov * tanh_f(c);

            if (p == 0) sh_h[u] = (_Float16)hval;
            __syncthreads();
        }
    }

    // ---- fc2 on final h ----
    if (l < 2) {
        float acc = fc2_b[l];
        #pragma unroll
        for (int k = 0; k < NH; ++k)
            acc = fmaf(fc2_w[l * NH + k], (float)sh_h[k], acc);
        out[(size_t)b * 2 + l] = acc;
    }
}

extern "C" void kernel_launch(void* const* d_in, const int* in_sizes, int n_in,
                              void* d_out, int out_size, void* d_ws, size_t ws_size,
                              hipStream_t stream) {
    const float* x     = (const float*)d_in[0];
    const float* fc1_w = (const float*)d_in[1];
    const float* fc1_b = (const float*)d_in[2];
    const float* w_ih  = (const float*)d_in[3];
    const float* w_hh  = (const float*)d_in[4];
    const float* b_ih  = (const float*)d_in[5];
    const float* b_hh  = (const float*)d_in[6];
    const float* fc2_w = (const float*)d_in[7];
    const float* fc2_b = (const float*)d_in[8];
    float* out = (float*)d_out;

    const int B = in_sizes[0] / (TT * IN);
    lstm_fused<<<dim3(B), dim3(64), 0, stream>>>(
        x, fc1_w, fc1_b, w_ih, w_hh, b_ih, b_hh, fc2_w, fc2_b, out);
}

// Round 9
// 152.755 us; speedup vs baseline: 1.4139x; 1.0062x over previous
//
#include <hip/hip_runtime.h>

#define TT  200
#define IN  5
#define NH  32
#define FC1 20
#define CH  64        // h20 chunk length (= wave size)
#define RS  12        // h20 chunk row stride in h2 units (48 B, 16B-aligned)

typedef _Float16 h2t __attribute__((ext_vector_type(2)));   // 4 B
typedef _Float16 h4t __attribute__((ext_vector_type(4)));   // 8 B
typedef _Float16 h8t __attribute__((ext_vector_type(8)));   // 16 B

#if __has_builtin(__builtin_amdgcn_fdot2)
#define FDOT2(a, b, c) __builtin_amdgcn_fdot2((a), (b), (c), false)
#else
__device__ __forceinline__ float FDOT2(h2t a, h2t b, float c) {
    return fmaf((float)a.x, (float)b.x, fmaf((float)a.y, (float)b.y, c));
}
#endif

__device__ __forceinline__ float sigm(float a) {
    return __builtin_amdgcn_rcpf(1.f + __expf(-a));
}
__device__ __forceinline__ float tanh_f(float a) {
    return fmaf(2.f, __builtin_amdgcn_rcpf(1.f + __expf(-2.f * a)), -1.f);
}

#define EXT2(dst, src, i0, i1) dst = __builtin_shufflevector(src, src, i0, i1)

// One wave per batch element. Lane l = (u = l&31, p = l>>5).
// Lane owns rows rA = u+32p (i|f) and rB = rA+64 (g|o), full K=52, as 52 f16
// pairs consumed by v_dot2_f32_f16 (f32 accumulate). Weights pinned via
// 32-bit volatile asm (non-rematerializable). h + h20 in LDS as f16; all
// in-loop cross-lane traffic is same-wave DS ops (FIFO) -> no barriers.
__global__ __attribute__((amdgpu_waves_per_eu(4, 4))) __launch_bounds__(64)
void lstm_fused(
    const float* __restrict__ x,      // [B,200,5]
    const float* __restrict__ fc1_w,  // [20,5]
    const float* __restrict__ fc1_b,  // [20]
    const float* __restrict__ w_ih,   // [128,20]
    const float* __restrict__ w_hh,   // [128,32]
    const float* __restrict__ b_ih,   // [128]
    const float* __restrict__ b_hh,   // [128]
    const float* __restrict__ fc2_w,  // [2,32]
    const float* __restrict__ fc2_b,  // [2]
    float* __restrict__ out)          // [B,2]
{
    const int b = blockIdx.x;
    const int l = threadIdx.x;
    const int u = l & 31;
    const int p = l >> 5;

    __shared__ __align__(16) h2t h20c[CH * RS];   // 3 KB
    __shared__ __align__(16) _Float16 sh_h[NH];   // 64 B

    // ---- load this lane's two weight rows as f16 pairs (52 VGPRs) ----
    const int rA = u + 32 * p;      // i (p=0) | f (p=1)
    const int rB = rA + 64;         // g (p=0) | o (p=1)
    h2t wA[26], wB[26];             // [w_ih: 10 pairs][w_hh: 16 pairs]
    {
        const float4* pa = (const float4*)(w_ih + rA * FC1);
        const float4* pb = (const float4*)(w_ih + rB * FC1);
        #pragma unroll
        for (int j = 0; j < 5; ++j) {
            float4 va = pa[j], vb = pb[j];
            wA[2*j]   = h2t{(_Float16)va.x, (_Float16)va.y};
            wA[2*j+1] = h2t{(_Float16)va.z, (_Float16)va.w};
            wB[2*j]   = h2t{(_Float16)vb.x, (_Float16)vb.y};
            wB[2*j+1] = h2t{(_Float16)vb.z, (_Float16)vb.w};
        }
        const float4* ca = (const float4*)(w_hh + rA * NH);
        const float4* cb = (const float4*)(w_hh + rB * NH);
        #pragma unroll
        for (int j = 0; j < 8; ++j) {
            float4 va = ca[j], vb = cb[j];
            wA[10+2*j]   = h2t{(_Float16)va.x, (_Float16)va.y};
            wA[10+2*j+1] = h2t{(_Float16)va.z, (_Float16)va.w};
            wB[10+2*j]   = h2t{(_Float16)vb.x, (_Float16)vb.y};
            wB[10+2*j+1] = h2t{(_Float16)vb.z, (_Float16)vb.w};
        }
        // pin: 32-bit opaque values; volatile asm results cannot be remat'd
        #pragma unroll
        for (int j = 0; j < 26; ++j) {
            int tA = __builtin_bit_cast(int, wA[j]);
            int tB = __builtin_bit_cast(int, wB[j]);
            asm volatile("" : "+v"(tA));
            asm volatile("" : "+v"(tB));
            wA[j] = __builtin_bit_cast(h2t, tA);
            wB[j] = __builtin_bit_cast(h2t, tB);
        }
    }
    const float biasA = b_ih[rA] + b_hh[rA];
    const float biasB = b_ih[rB] + b_hh[rB];

    // second activation: tanh (p=0, g) vs sigmoid (p=1, o)
    const float An = (p == 0) ? 2.f : 1.f;
    const float Bn = (p == 0) ? -2.f : -1.f;
    const float Cn = (p == 0) ? -1.f : 0.f;

    // init h = 0
    if (l < 16) ((unsigned int*)sh_h)[l] = 0u;
    float c = 0.f;

    const float* xb = x + (size_t)b * (TT * IN);

    for (int tc = 0; tc < TT; tc += CH) {
        // ---- refill: lane l computes h20 for t = tc + l ----
        {
            const int t = tc + l;
            if (t < TT) {
                float xv[IN];
                #pragma unroll
                for (int i = 0; i < IN; ++i) xv[i] = xb[t * IN + i];
                h2t* row = h20c + (size_t)l * RS;
                #pragma unroll
                for (int j = 0; j < FC1; j += 2) {
                    float a0 = fc1_b[j], a1 = fc1_b[j + 1];
                    #pragma unroll
                    for (int i = 0; i < IN; ++i) {
                        a0 = fmaf(fc1_w[j * IN + i],       xv[i], a0);
                        a1 = fmaf(fc1_w[(j + 1) * IN + i], xv[i], a1);
                    }
                    row[j >> 1] = h2t{(_Float16)fmaxf(a0, 0.f),
                                      (_Float16)fmaxf(a1, 0.f)};
                }
            }
        }
        __syncthreads();   // once per 64 steps

        const int te = (TT - tc < CH) ? (TT - tc) : CH;
        for (int k = 0; k < te; ++k) {
            // gather xin = [h20(10 pairs) | h(16 pairs)] via uniform DS reads
            h2t xin[26];
            {
                const h2t* row = h20c + (size_t)k * RS;
                h8t r0 = *(const h8t*)(row);       // pairs 0-3
                h8t r1 = *(const h8t*)(row + 4);   // pairs 4-7
                h4t r2 = *(const h4t*)(row + 8);   // pairs 8-9
                EXT2(xin[0], r0, 0, 1);  EXT2(xin[1], r0, 2, 3);
                EXT2(xin[2], r0, 4, 5);  EXT2(xin[3], r0, 6, 7);
                EXT2(xin[4], r1, 0, 1);  EXT2(xin[5], r1, 2, 3);
                EXT2(xin[6], r1, 4, 5);  EXT2(xin[7], r1, 6, 7);
                EXT2(xin[8], r2, 0, 1);  EXT2(xin[9], r2, 2, 3);
                const h8t* hp = (const h8t*)sh_h;
                h8t h0 = hp[0], h1 = hp[1], h2 = hp[2], h3 = hp[3];
                EXT2(xin[10], h0, 0, 1); EXT2(xin[11], h0, 2, 3);
                EXT2(xin[12], h0, 4, 5); EXT2(xin[13], h0, 6, 7);
                EXT2(xin[14], h1, 0, 1); EXT2(xin[15], h1, 2, 3);
                EXT2(xin[16], h1, 4, 5); EXT2(xin[17], h1, 6, 7);
                EXT2(xin[18], h2, 0, 1); EXT2(xin[19], h2, 2, 3);
                EXT2(xin[20], h2, 4, 5); EXT2(xin[21], h2, 6, 7);
                EXT2(xin[22], h3, 0, 1); EXT2(xin[23], h3, 2, 3);
                EXT2(xin[24], h3, 4, 5); EXT2(xin[25], h3, 6, 7);
            }

            // 52 dot2, 2 chains per row
            float aA0 = biasA, aA1 = 0.f, aB0 = biasB, aB1 = 0.f;
            #pragma unroll
            for (int j = 0; j < 26; j += 2) {
                aA0 = FDOT2(wA[j],     xin[j],     aA0);
                aA1 = FDOT2(wA[j + 1], xin[j + 1], aA1);
                aB0 = FDOT2(wB[j],     xin[j],     aB0);
                aB1 = FDOT2(wB[j + 1], xin[j + 1], aB1);
            }
            const float aA = aA0 + aA1;
            const float aB = aB0 + aB1;

            // s0 = sigmoid(aA) [i|f]; s1 = tanh/sigmoid(aB) [g|o]
            const float s0 = sigm(aA);
            const float e1 = __expf(Bn * aB);
            const float s1 = fmaf(An, __builtin_amdgcn_rcpf(1.f + e1), Cn);

            // exchange with the other half (same-wave ds_bpermute, FIFO)
            const float x0 = __shfl_xor(s0, 32);
            const float x1 = __shfl_xor(s1, 32);

            // mirrored update: all lanes compute identical c / hval for dim u
            const float ig = (p == 0) ? (s0 * s1) : (x0 * x1);  // i*g
            const float fv = (p == 0) ? x0 : s0;                // f
            const float ov = (p == 0) ? x1 : s1;                // o
            c = fmaf(fv, c, ig);
            const float hval = ov * tanh_f(c);

            if (p == 0) sh_h[u] = (_Float16)hval;
            asm volatile("" ::: "memory");  // compiler fence; wave DS is FIFO
        }
    }

    // ---- fc2 on final h ----
    if (l < 2) {
        float acc = fc2_b[l];
        #pragma unroll
        for (int k = 0; k < NH; ++k)
            acc = fmaf(fc2_w[l * NH + k], (float)sh_h[k], acc);
        out[(size_t)b * 2 + l] = acc;
    }
}

extern "C" void kernel_launch(void* const* d_in, const int* in_sizes, int n_in,
                              void* d_out, int out_size, void* d_ws, size_t ws_size,
                              hipStream_t stream) {
    const float* x     = (const float*)d_in[0];
    const float* fc1_w = (const float*)d_in[1];
    const float* fc1_b = (const float*)d_in[2];
    const float* w_ih  = (const float*)d_in[3];
    const float* w_hh  = (const float*)d_in[4];
    const float* b_ih  = (const float*)d_in[5];
    const float* b_hh  = (const float*)d_in[6];
    const float* fc2_w = (const float*)d_in[7];
    const float* fc2_b = (const float*)d_in[8];
    float* out = (float*)d_out;

    const int B = in_sizes[0] / (TT * IN);
    lstm_fused<<<dim3(B), dim3(64), 0, stream>>>(
        x, fc1_w, fc1_b, w_ih, w_hh, b_ih, b_hh, fc2_w, fc2_b, out);
}